// Round 1
// 278.187 us; speedup vs baseline: 1.0273x; 1.0273x over previous
//
#include <hip/hip_runtime.h>

typedef __attribute__((ext_vector_type(8))) __bf16 bf16x8;
typedef __attribute__((ext_vector_type(4))) __bf16 bf16x4;
typedef __attribute__((ext_vector_type(4))) float f32x4;

#define GLDS(g, l) __builtin_amdgcn_global_load_lds( \
    (__attribute__((address_space(1))) void*)(void*)(g), \
    (__attribute__((address_space(3))) void*)(void*)(l), 16, 0, 0)

constexpr int T_REAL = 2049;   // sequence length
constexpr int Tp     = 2112;   // padded to 33*64
constexpr int Mreal  = 8196;   // 4*2049
constexpr int Mp     = 8448;   // padded to 33*256 (256-tile GEMM)
constexpr int GK     = 1024;   // C

// q pre-scale: 1/sqrt(64) * log2(e)  -> softmax runs in exp2 domain
constexpr float QSCALE = 0.125f * 1.4426950408889634f;

// ---------------- convert x (fp32 -> bf16, zero-pad rows) ----------------
__global__ __launch_bounds__(256) void cvt_x(const float* __restrict__ x,
                                             __bf16* __restrict__ xb) {
    size_t i = ((size_t)blockIdx.x * 256 + threadIdx.x) * 4;
    float4 v = make_float4(0.f, 0.f, 0.f, 0.f);
    if (i < (size_t)Mreal * GK) v = *(const float4*)(x + i);
    bf16x4 o;
    o.x = (__bf16)v.x; o.y = (__bf16)v.y; o.z = (__bf16)v.z; o.w = (__bf16)v.w;
    *(bf16x4*)(xb + i) = o;
}

// ---------------- transpose weights (K x N fp32 -> N x K bf16) ----------------
__global__ __launch_bounds__(256) void transpose_w(const float* __restrict__ W,
                                                   __bf16* __restrict__ Wt,
                                                   int K, int N) {
    __shared__ float tile[64][65];
    const int n0 = blockIdx.x * 64, k0 = blockIdx.y * 64;
    const int tx = threadIdx.x & 63, ty = threadIdx.x >> 6;
#pragma unroll
    for (int j = 0; j < 16; j++) {
        int rk = ty + j * 4;
        tile[rk][tx] = W[(size_t)(k0 + rk) * N + n0 + tx];
    }
    __syncthreads();
#pragma unroll
    for (int j = 0; j < 16; j++) {
        int rn = ty + j * 4;
        Wt[(size_t)(n0 + rn) * K + k0 + tx] = (__bf16)tile[tx][rn];
    }
}

// ---------------- transpose v: [bh][t][d] -> [bh][d][t] ----------------
__global__ __launch_bounds__(256) void transpose_v(const __bf16* __restrict__ v,
                                                   __bf16* __restrict__ vT) {
    __shared__ __bf16 tl[64][72];   // stride 72 els = 144B rows, 16B-aligned
    const int bh = blockIdx.y, t0 = blockIdx.x * 64;
    const int tid = threadIdx.x;
    const __bf16* src = v + ((size_t)bh * Tp + t0) * 64;
    {
        const int r = tid >> 3, c = (tid & 7) * 8;
        *(bf16x8*)&tl[r][c]      = *(const bf16x8*)(src + r * 64 + c);
        *(bf16x8*)&tl[r + 32][c] = *(const bf16x8*)(src + (r + 32) * 64 + c);
    }
    __syncthreads();
    __bf16* dst = vT + (size_t)bh * 64 * Tp + t0;
    {
        const int d = tid >> 3, tc = (tid & 7) * 8;
        bf16x8 a, b;
#pragma unroll
        for (int i = 0; i < 8; i++) {
            a[i] = tl[tc + i][d];
            b[i] = tl[tc + i][d + 32];
        }
        *(bf16x8*)(dst + (size_t)d * Tp + tc)        = a;
        *(bf16x8*)(dst + (size_t)(d + 32) * Tp + tc) = b;
    }
}

// ---------------- 256x256x64 8-phase pipelined QKV GEMM ----------------
// m201-template port in plain HIP. 8 waves (2M x 4N), per-wave 128x64 C.
// Interleaved frag mapping: m-frag f -> row (f&3)*32 + wr*16 + (f>>2)*128,
// n-frag n -> col (n&1)*64 + wc*16 + (n>>1)*128, so each phase touches exactly
// one A-half and one B-half of the current K-tile:
//   q1: A0 x B0 (reads A m0-3 + B n0-1)     q2: A0 x B1 (reads B n2-3)
//   q3: A1 x B1 (reads A m4-7)              q4: A1 x B0 (register reuse, 0 reads)
// LDS-read lifetimes: A0,B0 die after q1; B1 after q2; A1 after q3 -> staging
// (one half per phase, slot free >=1 barrier before issue):
//   q1 stages A1(T+1), B0(T+1);  q3 stages A0(T+2);  q4 stages B1(T+2)
// One counted vmcnt(4) per K-tile (end of q4) leaves the q3/q4 stages in
// flight; never drains to 0 in the main loop (tail tiles: vmcnt(0)).
__global__ __launch_bounds__(512)
void gemm256(const __bf16* __restrict__ A, const __bf16* __restrict__ Bt,
             __bf16* __restrict__ qout, __bf16* __restrict__ kout,
             __bf16* __restrict__ vout) {
    __shared__ __align__(16) __bf16 As[2][16384];   // 2 x 32 KB
    __shared__ __align__(16) __bf16 Bs[2][16384];   // 2 x 32 KB

    const int tid = threadIdx.x, lane = tid & 63, w = tid >> 6;
    const int wr = w >> 2, wc = w & 3;
    const int quad = lane >> 4, l15 = lane & 15, l7 = l15 & 7;
    const int m0 = blockIdx.y * 256, n0 = blockIdx.x * 256;

    // staging geometry: thread -> (row sr, chunk tid&7), source pre-swizzled
    // (rule #21: linear LDS dest, inverse-swizzled global src, swizzled read)
    const int sr = tid >> 3;                       // 0..63
    const int sc = ((tid & 7) ^ (sr & 7)) * 8;
    const __bf16* ag = A  + (size_t)(m0 + sr) * GK + sc;
    const __bf16* bg = Bt + (size_t)(n0 + sr) * GK + sc;
    const int ldst = tid * 8;                      // per-wave contiguous, lane*16B

#define STG_A(T, h) do { const __bf16* s_ = ag + (size_t)(h) * 128 * GK + (T) * 64; \
    GLDS(s_, &As[(T) & 1][(h) * 8192 + ldst]); \
    GLDS(s_ + (size_t)64 * GK, &As[(T) & 1][(h) * 8192 + 4096 + ldst]); } while (0)
#define STG_B(T, h) do { const __bf16* s_ = bg + (size_t)(h) * 128 * GK + (T) * 64; \
    GLDS(s_, &Bs[(T) & 1][(h) * 8192 + ldst]); \
    GLDS(s_ + (size_t)64 * GK, &Bs[(T) & 1][(h) * 8192 + 4096 + ldst]); } while (0)

    f32x4 acc[8][4] = {};
    bf16x8 a[8], b0[4], b1[4];

    // prologue: issue order == steady-state age order
    STG_A(0, 0); STG_B(0, 1); STG_A(0, 1); STG_B(0, 0); STG_A(1, 0); STG_B(1, 1);
    asm volatile("s_waitcnt vmcnt(4)" ::: "memory");   // tile 0 landed; A0/B1(1) in flight
    __builtin_amdgcn_s_barrier();

    constexpr int NT = GK / 64;   // 16

#pragma unroll 1
    for (int T = 0; T < NT; ++T) {
        const int p = T & 1;

        // ---------- phase 1: read A0 (m0-3) + B0 (n0-1); stage A1/B0(T+1) ----------
#pragma unroll
        for (int f = 0; f < 4; ++f) {
            const int R = f * 32 + wr * 16 + l15;
            a[f * 2 + 0] = *(const bf16x8*)&As[p][R * 64 + ((quad ^ l7) * 8)];
            a[f * 2 + 1] = *(const bf16x8*)&As[p][R * 64 + (((4 + quad) ^ l7) * 8)];
        }
#pragma unroll
        for (int n = 0; n < 2; ++n) {
            const int R = n * 64 + wc * 16 + l15;
            b0[n * 2 + 0] = *(const bf16x8*)&Bs[p][R * 64 + ((quad ^ l7) * 8)];
            b0[n * 2 + 1] = *(const bf16x8*)&Bs[p][R * 64 + (((4 + quad) ^ l7) * 8)];
        }
        if (T + 1 < NT) { STG_A(T + 1, 1); STG_B(T + 1, 0); }
        __builtin_amdgcn_s_barrier();
        asm volatile("s_waitcnt lgkmcnt(0)" ::: "memory");
        __builtin_amdgcn_sched_barrier(0);
        __builtin_amdgcn_s_setprio(1);
#pragma unroll
        for (int f = 0; f < 4; ++f)
#pragma unroll
            for (int n = 0; n < 2; ++n) {
                acc[f][n] = __builtin_amdgcn_mfma_f32_16x16x32_bf16(a[f*2+0], b0[n*2+0], acc[f][n], 0, 0, 0);
                acc[f][n] = __builtin_amdgcn_mfma_f32_16x16x32_bf16(a[f*2+1], b0[n*2+1], acc[f][n], 0, 0, 0);
            }
        __builtin_amdgcn_s_setprio(0);
        __builtin_amdgcn_s_barrier();

        // ---------- phase 2: read B1 (n2-3); MFMA m0-3 x n2-3 ----------
#pragma unroll
        for (int n = 0; n < 2; ++n) {
            const int R = 128 + n * 64 + wc * 16 + l15;
            b1[n * 2 + 0] = *(const bf16x8*)&Bs[p][R * 64 + ((quad ^ l7) * 8)];
            b1[n * 2 + 1] = *(const bf16x8*)&Bs[p][R * 64 + (((4 + quad) ^ l7) * 8)];
        }
        __builtin_amdgcn_s_barrier();
        asm volatile("s_waitcnt lgkmcnt(0)" ::: "memory");
        __builtin_amdgcn_sched_barrier(0);
        __builtin_amdgcn_s_setprio(1);
#pragma unroll
        for (int f = 0; f < 4; ++f)
#pragma unroll
            for (int n = 0; n < 2; ++n) {
                acc[f][2+n] = __builtin_amdgcn_mfma_f32_16x16x32_bf16(a[f*2+0], b1[n*2+0], acc[f][2+n], 0, 0, 0);
                acc[f][2+n] = __builtin_amdgcn_mfma_f32_16x16x32_bf16(a[f*2+1], b1[n*2+1], acc[f][2+n], 0, 0, 0);
            }
        __builtin_amdgcn_s_setprio(0);
        __builtin_amdgcn_s_barrier();

        // ---------- phase 3: read A1 (m4-7); stage A0(T+2); MFMA m4-7 x n2-3 ----------
#pragma unroll
        for (int f = 0; f < 4; ++f) {
            const int R = 128 + f * 32 + wr * 16 + l15;
            a[f * 2 + 0] = *(const bf16x8*)&As[p][R * 64 + ((quad ^ l7) * 8)];
            a[f * 2 + 1] = *(const bf16x8*)&As[p][R * 64 + (((4 + quad) ^ l7) * 8)];
        }
        if (T + 2 < NT) STG_A(T + 2, 0);
        __builtin_amdgcn_s_barrier();
        asm volatile("s_waitcnt lgkmcnt(0)" ::: "memory");
        __builtin_amdgcn_sched_barrier(0);
        __builtin_amdgcn_s_setprio(1);
#pragma unroll
        for (int f = 0; f < 4; ++f)
#pragma unroll
            for (int n = 0; n < 2; ++n) {
                acc[4+f][2+n] = __builtin_amdgcn_mfma_f32_16x16x32_bf16(a[f*2+0], b1[n*2+0], acc[4+f][2+n], 0, 0, 0);
                acc[4+f][2+n] = __builtin_amdgcn_mfma_f32_16x16x32_bf16(a[f*2+1], b1[n*2+1], acc[4+f][2+n], 0, 0, 0);
            }
        __builtin_amdgcn_s_setprio(0);
        __builtin_amdgcn_s_barrier();

        // ---------- phase 4: stage B1(T+2); MFMA m4-7 x n0-1; counted vmcnt ----------
        if (T + 2 < NT) STG_B(T + 2, 1);
        __builtin_amdgcn_s_barrier();
        asm volatile("s_waitcnt lgkmcnt(0)" ::: "memory");
        __builtin_amdgcn_sched_barrier(0);
        __builtin_amdgcn_s_setprio(1);
#pragma unroll
        for (int f = 0; f < 4; ++f)
#pragma unroll
            for (int n = 0; n < 2; ++n) {
                acc[4+f][n] = __builtin_amdgcn_mfma_f32_16x16x32_bf16(a[f*2+0], b0[n*2+0], acc[4+f][n], 0, 0, 0);
                acc[4+f][n] = __builtin_amdgcn_mfma_f32_16x16x32_bf16(a[f*2+1], b0[n*2+1], acc[4+f][n], 0, 0, 0);
            }
        __builtin_amdgcn_s_setprio(0);
        if (T < NT - 2) { asm volatile("s_waitcnt vmcnt(4)" ::: "memory"); }
        else            { asm volatile("s_waitcnt vmcnt(0)" ::: "memory"); }
        __builtin_amdgcn_s_barrier();
    }
#undef STG_A
#undef STG_B

    // ---------- epilogue: per-m-frag LDS transpose -> coalesced bf16x8 stores ----
    const int which = n0 >> 10;                       // block-uniform: q/k/v
    __bf16* op = (which == 0) ? qout : (which == 1) ? kout : vout;
    const float scl = (which == 0) ? QSCALE : 1.0f;
    __bf16* ep = &As[0][0];                           // 32 x 264 bf16 = 16.5 KB
    const int rr = tid >> 4, cc = tid & 15;
#pragma unroll
    for (int f = 0; f < 8; ++f) {
        __syncthreads();
#pragma unroll
        for (int n = 0; n < 4; ++n) {
            const int col = (n & 1) * 64 + wc * 16 + (n >> 1) * 128 + l15;
#pragma unroll
            for (int r = 0; r < 4; ++r)
                ep[(wr * 16 + quad * 4 + r) * 264 + col] = (__bf16)(acc[f][n][r] * scl);
        }
        __syncthreads();
        const int m = m0 + (f & 3) * 32 + (f >> 2) * 128 + rr;
        if (m < Mreal) {
            const int b = m / T_REAL;
            const int t = m - b * T_REAL;
#pragma unroll
            for (int g = 0; g < 2; ++g) {
                const int c8 = (cc + g * 16) * 8;
                bf16x8 vv = *(const bf16x8*)&ep[rr * 264 + c8];
                const int gc = n0 + c8;
                const int h = (gc >> 6) & 15;
                *(bf16x8*)&op[((size_t)(b * 16 + h) * Tp + t) * 64 + (gc & 63)] = vv;
            }
        }
    }
}

// ---------------- 128x128x64 bf16 GEMM, LDS round-trip epilogues ----------------
// (retained for the projection GEMM: N=1024 gives too few 256^2 blocks)
template <int EPI>
__global__ __launch_bounds__(256)
void gemm128(const __bf16* __restrict__ A, const __bf16* __restrict__ Bt,
             float* __restrict__ outp,
             __bf16* __restrict__ qout, __bf16* __restrict__ kout,
             __bf16* __restrict__ vout) {
    __shared__ __bf16 As[128 * 64];   // 16 KB
    __shared__ __bf16 Bs[128 * 64];   // 16 KB

    const int tid = threadIdx.x, lane = tid & 63, w = tid >> 6;
    const int wr = w >> 1, wc = w & 1;
    const int quad = lane >> 4, l15 = lane & 15, l7 = l15 & 7;
    const int m0 = blockIdx.y * 128, n0 = blockIdx.x * 128;

    const int row0 = w * 32 + (lane >> 3);
    const int gc8 = ((lane & 7) ^ ((lane >> 3) & 7)) * 8;
    const __bf16* agp = A + (size_t)(m0 + row0) * GK + gc8;
    const __bf16* bgp = Bt + (size_t)(n0 + row0) * GK + gc8;
    __bf16* lap = &As[(w * 256 + lane) * 8];
    __bf16* lbp = &Bs[(w * 256 + lane) * 8];

    f32x4 acc[4][4] = {};

    for (int k0 = 0; k0 < GK; k0 += 64) {
#pragma unroll
        for (int s = 0; s < 4; s++) {
            GLDS(agp + (size_t)s * 8 * GK + k0, lap + s * 512);
            GLDS(bgp + (size_t)s * 8 * GK + k0, lbp + s * 512);
        }
        __syncthreads();
#pragma unroll
        for (int kk = 0; kk < 2; kk++) {
            bf16x8 fa[4], fb[4];
#pragma unroll
            for (int i = 0; i < 4; i++)
                fa[i] = *(const bf16x8*)&As[(wr * 64 + i * 16 + l15) * 64 + (((kk * 4 + quad) ^ l7) * 8)];
#pragma unroll
            for (int j = 0; j < 4; j++)
                fb[j] = *(const bf16x8*)&Bs[(wc * 64 + j * 16 + l15) * 64 + (((kk * 4 + quad) ^ l7) * 8)];
#pragma unroll
            for (int i = 0; i < 4; i++)
#pragma unroll
                for (int j = 0; j < 4; j++)
                    acc[i][j] = __builtin_amdgcn_mfma_f32_16x16x32_bf16(fa[i], fb[j], acc[i][j], 0, 0, 0);
        }
        __syncthreads();
    }

    if constexpr (EPI == 0) {
        const int which = n0 >> 10;                   // block-uniform
        const int h = ((n0 + wc * 64) >> 6) & 15;
        __bf16* op = (which == 0) ? qout : (which == 1) ? kout : vout;
        const float scl = (which == 0) ? QSCALE : 1.0f;
        __bf16* wls = &As[w * 2048];                  // 32 rows x 64 els / pass
#pragma unroll
        for (int p = 0; p < 2; p++) {
            if (p) __syncthreads();
#pragma unroll
            for (int i2 = 0; i2 < 2; i2++)
#pragma unroll
                for (int j = 0; j < 4; j++)
#pragma unroll
                    for (int r = 0; r < 4; r++) {
                        const int lrow = i2 * 16 + quad * 4 + r;
                        const int cX = (j * 2 + (l15 >> 3)) ^ (lrow & 7);
                        wls[lrow * 64 + cX * 8 + (l15 & 7)] =
                            (__bf16)(acc[p * 2 + i2][j][r] * scl);
                    }
            __syncthreads();
#pragma unroll
            for (int it = 0; it < 4; it++) {
                const int lrow = (lane >> 3) + it * 8;
                bf16x8 vv = *(const bf16x8*)&wls[lrow * 64 + (((lane & 7) ^ (lrow & 7)) * 8)];
                const int m = m0 + wr * 64 + p * 32 + lrow;
                if (m < Mreal) {
                    const int b = m / T_REAL;
                    const int t = m - b * T_REAL;
                    *(bf16x8*)&op[(((size_t)(b * 16 + h)) * Tp + t) * 64 + (lane & 7) * 8] = vv;
                }
            }
        }
    } else {
        float* wlf = (float*)&As[0] + w * 1024;       // 16 rows x 64 f32 / pass
#pragma unroll
        for (int p = 0; p < 4; p++) {
            if (p) __syncthreads();
#pragma unroll
            for (int j = 0; j < 4; j++)
#pragma unroll
                for (int r = 0; r < 4; r++) {
                    const int lrow = quad * 4 + r;
                    const int cX = (j * 4 + (l15 >> 2)) ^ (lrow & 7);
                    wlf[lrow * 64 + cX * 4 + (l15 & 3)] = acc[p][j][r];
                }
            __syncthreads();
#pragma unroll
            for (int it = 0; it < 4; it++) {
                const int lrow = lane >> 2;
                const int c = (lane & 3) + it * 4;
                f32x4 vv = *(const f32x4*)&wlf[lrow * 64 + ((c ^ (lrow & 7)) * 4)];
                const int m = m0 + wr * 64 + p * 16 + lrow;
                if (m < Mreal)
                    *(f32x4*)&outp[(size_t)m * 1024 + n0 + wc * 64 + c * 4] = vv;
            }
        }
    }
}

// ---------------- flash attention v6: 512-thr blocks, paired q-tiles ----------------
// 8 waves share one K/V staging: waves 0-3 -> q-tile A, waves 4-7 -> q-tile B.
// Pairs (0,32),(31,30),...,(3,2),(1,-): kv extents nearly equal per pair
// (~2% wasted iterations, skipped per-wave; barriers always honored).
// LDS = K/V dbuf 32 KB + 8x2 KB Pq = 48 KB -> 3 blocks/CU = 24 waves (6/SIMD,
// was 4/SIMD) with NO VGPR pressure change (the round-6 spill lesson: keep
// GLDS double-buffer, never reg-prefetch). Staging + barriers per unit work
// halve vs 64-q blocks. Heavy slots launch first; bh=(zz&7)*8+(zz>>3) keeps
// a bh's blocks on one XCD.
__global__ __launch_bounds__(512, 6)
void attn(const __bf16* __restrict__ q, const __bf16* __restrict__ kk,
          const __bf16* __restrict__ vT, __bf16* __restrict__ y) {
    __shared__ __bf16 Ks[2][64 * 64];
    __shared__ __bf16 Vs[2][64 * 64];     // [d][kv]
    __shared__ __bf16 Pq[8][16 * 64];     // per-wave P^T as [q][kv]

    static const int QA[17] = {0,31,29,27,25,23,21,19,17,15,13,11,9,7,5,3,1};
    static const int QB[17] = {32,30,28,26,24,22,20,18,16,14,12,10,8,6,4,2,-1};

    const int tid = threadIdx.x, lane = tid & 63, w = tid >> 6;
    const int quad = lane >> 4, l15 = lane & 15;
    const int l7 = l15 & 7;
    const int z = blockIdx.x;
    const int slot = z >> 6;
    const int zz = z & 63;
    const int bh = (zz & 7) * 8 + (zz >> 3);

    const int qtA = QA[slot];
    const int qt = (w < 4) ? qtA : QB[slot];       // this wave's q-tile
    const bool active = qt >= 0;
    const int qts = active ? qt : 0;               // safe index for addresses
    const int q0 = qts * 64;
    const int qg = q0 + (w & 3) * 16 + l15;        // this lane's q-row
    const int myNt = (qts == 0) ? 32 : qts;        // last kv-tile this wave needs
    const int ntmaxB = (qtA == 0) ? 32 : qtA;      // block kv loop bound

    const __bf16* kgb = kk + (size_t)bh * Tp * 64;
    const __bf16* vgb = vT + (size_t)bh * 64 * Tp;
    const int b = bh >> 4, h = bh & 15;

    // staging: 512 threads x one 16B chunk each for K and V (XOR row swizzle)
    const int r0 = tid >> 3;                       // 0..63
    const int s0 = ((tid & 7) ^ (r0 & 7)) * 8;
    const int koff = r0 * 64 + s0;
    const int voff = r0 * Tp + s0;

    bf16x8 qa0, qa1;
    {
        const __bf16* qp = q + ((size_t)bh * Tp + qg) * 64 + quad * 8;
        qa0 = *(const bf16x8*)qp;
        qa1 = *(const bf16x8*)(qp + 32);
    }

    f32x4 o[4] = {};                 // O^T frags: d = nf*16+quad*4+r, q = l15
    float mrow = -3e38f, lrow = 0.f;

    // prefetch kv tile 0 -> buf 0
    GLDS(kgb + koff, &Ks[0][tid * 8]);
    GLDS(vgb + voff, &Vs[0][tid * 8]);

    int cur = 0;
    for (int nt = 0; nt <= ntmaxB; ++nt) {
        __syncthreads();   // implicit vmcnt(0): cur buffer staged; prev reads done
        if (nt < ntmaxB) {
            GLDS(kgb + (size_t)(nt + 1) * 4096 + koff, &Ks[cur ^ 1][tid * 8]);
            GLDS(vgb + (size_t)(nt + 1) * 64 + voff, &Vs[cur ^ 1][tid * 8]);
        }
        if (active && nt <= myNt) {
            const int kv0 = nt * 64;

            // S^T = K * Q^T : st[j] rows kv = j*16+quad*4+r, col q = l15
            f32x4 st[4];
#pragma unroll
            for (int j = 0; j < 4; j++) {
                const __bf16* krow = &Ks[cur][(j * 16 + l15) * 64];
                bf16x8 klo = *(const bf16x8*)(krow + ((quad ^ l7) * 8));
                bf16x8 khi = *(const bf16x8*)(krow + (((quad + 4) ^ l7) * 8));
                f32x4 zzv = {0.f, 0.f, 0.f, 0.f};
                zzv = __builtin_amdgcn_mfma_f32_16x16x32_bf16(klo, qa0, zzv, 0, 0, 0);
                st[j] = __builtin_amdgcn_mfma_f32_16x16x32_bf16(khi, qa1, zzv, 0, 0, 0);
            }

            if (nt >= qts) {   // mask only on/past the diagonal (wave-uniform)
#pragma unroll
                for (int j = 0; j < 4; j++)
#pragma unroll
                    for (int r = 0; r < 4; r++) {
                        const int kvg = kv0 + j * 16 + quad * 4 + r;
                        const bool valid = (kvg <= qg) || (qg == 0 && kvg < T_REAL);
                        st[j][r] = valid ? st[j][r] : -1e30f;
                    }
            }

            // online softmax (exp2 domain), per-lane scalar state
            float mx = -3e38f;
#pragma unroll
            for (int j = 0; j < 4; j++)
#pragma unroll
                for (int r = 0; r < 4; r++) mx = fmaxf(mx, st[j][r]);
            mx = fmaxf(mx, __shfl_xor(mx, 16));
            mx = fmaxf(mx, __shfl_xor(mx, 32));
            const float mn = fmaxf(mrow, mx);
            const float alpha = __builtin_amdgcn_exp2f(mrow - mn);
            mrow = mn;

            float rs = 0.f;
            bf16x4 pk[4];
#pragma unroll
            for (int j = 0; j < 4; j++) {
                float p0 = __builtin_amdgcn_exp2f(st[j][0] - mn);
                float p1 = __builtin_amdgcn_exp2f(st[j][1] - mn);
                float p2 = __builtin_amdgcn_exp2f(st[j][2] - mn);
                float p3 = __builtin_amdgcn_exp2f(st[j][3] - mn);
                rs += (p0 + p1) + (p2 + p3);
                pk[j].x = (__bf16)p0; pk[j].y = (__bf16)p1;
                pk[j].z = (__bf16)p2; pk[j].w = (__bf16)p3;
            }
            rs += __shfl_xor(rs, 16);
            rs += __shfl_xor(rs, 32);
            lrow = lrow * alpha + rs;
#pragma unroll
            for (int nf = 0; nf < 4; nf++)
#pragma unroll
                for (int r = 0; r < 4; r++) o[nf][r] *= alpha;

            // P^T -> per-wave LDS as [q=l15][kv], packed 8B stores
#pragma unroll
            for (int j = 0; j < 4; j++)
                *(bf16x4*)&Pq[w][l15 * 64 + (((2 * j + (quad >> 1)) ^ l7) * 8) + (quad & 1) * 4] = pk[j];

            // O^T += V^T * P^T
#pragma unroll
            for (int kc = 0; kc < 2; kc++) {
                bf16x8 pb = *(const bf16x8*)&Pq[w][l15 * 64 + (((kc * 4 + quad) ^ l7) * 8)];
#pragma unroll
                for (int nf = 0; nf < 4; nf++) {
                    bf16x8 va = *(const bf16x8*)&Vs[cur][(nf * 16 + l15) * 64 + (((kc * 4 + quad) ^ l7) * 8)];
                    o[nf] = __builtin_amdgcn_mfma_f32_16x16x32_bf16(va, pb, o[nf], 0, 0, 0);
                }
            }
        }
        cur ^= 1;
    }

    // y[b, t=qg, h*64 + nf*16+quad*4+r], packed 8B stores
    if (active && qg < T_REAL) {
        const float inv = 1.0f / lrow;
        __bf16* yp = y + ((size_t)(b * T_REAL + qg)) * 1024 + h * 64 + quad * 4;
#pragma unroll
        for (int nf = 0; nf < 4; nf++) {
            bf16x4 pko;
            pko.x = (__bf16)(o[nf][0] * inv);
            pko.y = (__bf16)(o[nf][1] * inv);
            pko.z = (__bf16)(o[nf][2] * inv);
            pko.w = (__bf16)(o[nf][3] * inv);
            *(bf16x4*)(yp + nf * 16) = pko;
        }
    }
}

// ---------------- launch ----------------
extern "C" void kernel_launch(void* const* d_in, const int* in_sizes, int n_in,
                              void* d_out, int out_size, void* d_ws, size_t ws_size,
                              hipStream_t stream) {
    const float* x  = (const float*)d_in[0];
    const float* Wa = (const float*)d_in[1];
    const float* Wp = (const float*)d_in[2];
    float* out = (float*)d_out;

    char* ws = (char*)d_ws;
    constexpr size_t SZ_XB  = (size_t)Mp * GK * 2;
    constexpr size_t SZ_WAT = (size_t)3072 * GK * 2;
    constexpr size_t SZ_WPT = (size_t)1024 * GK * 2;
    constexpr size_t SZ_QK  = (size_t)64 * Tp * 64 * 2;
    __bf16* xb   = (__bf16*)(ws);
    __bf16* WaT  = (__bf16*)(ws + SZ_XB);
    __bf16* WpT  = (__bf16*)(ws + SZ_XB + SZ_WAT);
    __bf16* qb   = (__bf16*)(ws + SZ_XB + SZ_WAT + SZ_WPT);
    __bf16* kb   = (__bf16*)(ws + SZ_XB + SZ_WAT + SZ_WPT + SZ_QK);
    __bf16* vTb  = (__bf16*)(ws + SZ_XB + SZ_WAT + SZ_WPT + 2 * SZ_QK);
    __bf16* shrd = (__bf16*)(ws + SZ_XB + SZ_WAT + SZ_WPT + 3 * SZ_QK);
    __bf16* vpre = shrd;   // v [bh][t][d], consumed by transpose_v before attn
    __bf16* yb   = shrd;   // attn output, written after vpre is dead

    cvt_x<<<(Mp * GK) / 1024, 256, 0, stream>>>(x, xb);
    transpose_w<<<dim3(48, 16), 256, 0, stream>>>(Wa, WaT, 1024, 3072);
    transpose_w<<<dim3(16, 16), 256, 0, stream>>>(Wp, WpT, 1024, 1024);

    gemm256<<<dim3(12, 33), 512, 0, stream>>>(xb, WaT, qb, kb, vpre);
    transpose_v<<<dim3(33, 64), 256, 0, stream>>>(vpre, vTb);
    attn<<<1088, 512, 0, stream>>>(qb, kb, vTb, yb);
    gemm128<1><<<dim3(8, 65), 256, 0, stream>>>(yb, WpT, out, nullptr, nullptr, nullptr);
}